// Round 3
// baseline (94.463 us; speedup 1.0000x reference)
//
#include <hip/hip_runtime.h>
#include <hip/hip_bf16.h>

// Problem constants (fixed by setup_inputs):
//   T=36, Q=2048, C=42 (num_classes=41), N=128
// Inputs (d_in order):
//   0: pred_logits  float32 [T*Q, C]
//   1: pred_boxes   float32 [T*Q, 4]   (cx,cy,w,h)
//   2: tgt_labels   int32   [N*T]
//   3: tgt_boxes    float32 [N*T, 4]
//   4: tgt_valid    int32   [N*T]
//   5: tgt_original_valid int32 [N*T]
// Output: float32 [Q, N] row-major, out[q*N+n]

constexpr int T = 36;
constexpr int Q = 2048;
constexpr int C = 42;
constexpr int N = 128;

// ---------------------------------------------------------------------------
// Kernel 1: row softmax of logits, written TRANSPOSED as P2[t][c][q].
// All 256 threads active in the reduction (4 threads per row), exp computed
// once (stored back into the tile). Transposed write makes kernel 2's
// class-prob gather fully coalesced.
// ---------------------------------------------------------------------------
__global__ __launch_bounds__(256) void softmax_transpose_kernel(
    const float* __restrict__ logits, float* __restrict__ P2) {
  constexpr int QB = 64;
  constexpr int LS = C + 1;  // 43: gcd(43,32)=1 -> conflict-free

  __shared__ float tile[QB * LS];
  __shared__ float s_max[4 * QB];
  __shared__ float s_sum[4 * QB];
  __shared__ float s_rinv[QB];

  const int t = blockIdx.y;
  const int q0 = blockIdx.x * QB;
  const int tid = threadIdx.x;

  // Coalesced load of 64 rows x 42 cols (contiguous in global).
  const float* src = logits + ((size_t)t * Q + q0) * C;
  for (int i = tid; i < QB * C; i += 256) {
    int r = i / C, c = i % C;
    tile[r * LS + c] = src[i];
  }
  __syncthreads();

  // 4 threads per row: col ranges {0..10, 11..21, 22..31, 32..41}.
  const int part = tid >> 6;
  const int row = tid & 63;
  const int c0 = (part < 2) ? part * 11 : 22 + (part - 2) * 10;
  const int c1 = (part < 2) ? c0 + 11 : c0 + 10;

  float m = -1e30f;
  for (int c = c0; c < c1; ++c) m = fmaxf(m, tile[row * LS + c]);
  s_max[part * QB + row] = m;
  __syncthreads();

  m = fmaxf(fmaxf(s_max[row], s_max[QB + row]),
            fmaxf(s_max[2 * QB + row], s_max[3 * QB + row]));
  float s = 0.f;
  for (int c = c0; c < c1; ++c) {
    float e = __expf(tile[row * LS + c] - m);
    tile[row * LS + c] = e;  // single exp: store for the write pass
    s += e;
  }
  s_sum[part * QB + row] = s;
  __syncthreads();

  if (part == 0) {
    float stot = s_sum[row] + s_sum[QB + row] + s_sum[2 * QB + row] +
                 s_sum[3 * QB + row];
    s_rinv[row] = 1.f / stot;
  }
  __syncthreads();

  // Coalesced transposed write: lanes share c, span 64 consecutive q.
  for (int i = tid; i < QB * C; i += 256) {
    int c = i >> 6;  // 0..41
    int r = i & 63;  // 0..63
    P2[(size_t)(t * C + c) * Q + q0 + r] = tile[r * LS + c] * s_rinv[r];
  }
}

// ---------------------------------------------------------------------------
// Kernel 2: cost[q,n] = sum_t valid*(l1 - prob - iou) / denom[n].
// One (q,n) per thread; block = 64 q-lanes x 4 n-subgroups; grid (32,32).
// Branch-free fully-unrolled t-loop: 36 independent L2 gathers in flight
// (was a 36-deep dependent load chain behind a branch). pred_boxes staged
// in LDS (stride-16B b128 reads, conflict-free); target metadata reads are
// wave-uniform broadcasts, id scalarized via readfirstlane.
// ---------------------------------------------------------------------------
__global__ __launch_bounds__(256, 4) void cost_kernel(
    const float* __restrict__ P2, const float* __restrict__ pred_boxes,
    const int* __restrict__ labels, const float* __restrict__ tboxes,
    const int* __restrict__ valid, const int* __restrict__ ovalid,
    float* __restrict__ out) {
  constexpr int NB = 4;
  constexpr int RES_STRIDE = NB + 1;  // 5: conflict-free

  const int q0 = blockIdx.x * 64;
  const int n0 = blockIdx.y * NB;
  const int tid = threadIdx.x;
  const int lane = tid & 63;  // q offset
  const int sub = tid >> 6;   // local n 0..3 (wave-uniform)
  const int q = q0 + lane;

  __shared__ float4 s_pb[T * 64];  // 36 KB: pred boxes for this q-tile
  __shared__ float4 s_tb[NB * T];
  __shared__ int s_idv[NB * T];  // (valid<<8) | id
  __shared__ float s_rden[NB];   // 1/denom
  __shared__ float s_res[64 * RES_STRIDE];

  // Stage pred_boxes: per t, 64 consecutive float4 (fully coalesced).
  for (int i = tid; i < T * 64; i += 256) {
    int t = i >> 6, l = i & 63;
    s_pb[t * 64 + l] = ((const float4*)pred_boxes)[t * Q + q0 + l];
  }
  // Stage target metadata for this block's 4 n's.
  for (int i = tid; i < NB * T; i += 256) {
    int n = n0 + i / T;
    int t = i % T;
    int g = n * T + t;
    s_idv[i] = ((ovalid[g] == 0) ? (C - 1) : labels[g]) | (valid[g] << 8);
    s_tb[i] = ((const float4*)tboxes)[g];
  }
  if (tid < NB) {
    int n = n0 + tid;
    int s = 0;
    for (int t = 0; t < T; ++t) s += valid[n * T + t];
    s_rden[tid] = 1.f / (float)s;
  }
  __syncthreads();

  float acc = 0.f;
  const float* probs_base = P2 + q;

#pragma unroll
  for (int t = 0; t < T; ++t) {
    // Wave-uniform: scalarize so the gather base is an SGPR.
    int pk = __builtin_amdgcn_readfirstlane(s_idv[sub * T + t]);
    int id = pk & 0xff;
    float v = (float)(pk >> 8);
    // Coalesced gather: 64 lanes -> 64 consecutive floats (one 256B line).
    float p = probs_base[(size_t)(t * C + id) * Q];
    float4 pb = s_pb[t * 64 + lane];
    float4 tb = s_tb[sub * T + t];  // wave-uniform broadcast

    float l1 = 0.25f * (fabsf(pb.x - tb.x) + fabsf(pb.y - tb.y) +
                        fabsf(pb.z - tb.z) + fabsf(pb.w - tb.w));
    float px1 = pb.x - 0.5f * pb.z, py1 = pb.y - 0.5f * pb.w;
    float px2 = pb.x + 0.5f * pb.z, py2 = pb.y + 0.5f * pb.w;
    float tx1 = tb.x - 0.5f * tb.z, ty1 = tb.y - 0.5f * tb.w;
    float tx2 = tb.x + 0.5f * tb.z, ty2 = tb.y + 0.5f * tb.w;
    float iw = fmaxf(fminf(px2, tx2) - fmaxf(px1, tx1), 0.f);
    float ih = fmaxf(fminf(py2, ty2) - fmaxf(py1, ty1), 0.f);
    float inter = iw * ih;
    float uni = pb.z * pb.w + tb.z * tb.w - inter;
    // Branch-free (matches reference semantics incl. valid=0 exactly).
    acc += v * (l1 - p - inter / uni);
  }

  // Transpose through LDS -> coalesced float4 output stores.
  s_res[lane * RES_STRIDE + sub] = acc * s_rden[sub];
  __syncthreads();

  if (tid < 64) {
    float4 o;
    o.x = s_res[tid * RES_STRIDE + 0];
    o.y = s_res[tid * RES_STRIDE + 1];
    o.z = s_res[tid * RES_STRIDE + 2];
    o.w = s_res[tid * RES_STRIDE + 3];
    *(float4*)(out + (size_t)(q0 + tid) * N + n0) = o;
  }
}

extern "C" void kernel_launch(void* const* d_in, const int* in_sizes, int n_in,
                              void* d_out, int out_size, void* d_ws, size_t ws_size,
                              hipStream_t stream) {
  const float* logits = (const float*)d_in[0];
  const float* pboxes = (const float*)d_in[1];
  const int* labels = (const int*)d_in[2];
  const float* tboxes = (const float*)d_in[3];
  const int* valid = (const int*)d_in[4];
  const int* ovalid = (const int*)d_in[5];
  float* out = (float*)d_out;

  // Workspace: transposed probs P2[T][C][Q] = 36*42*2048*4 B = 12.4 MB.
  float* P2 = (float*)d_ws;

  dim3 g1(Q / 64, T);
  softmax_transpose_kernel<<<g1, 256, 0, stream>>>(logits, P2);

  dim3 g2(Q / 64, N / 4);
  cost_kernel<<<g2, 256, 0, stream>>>(P2, pboxes, labels, tboxes, valid, ovalid, out);
}

// Round 4
// 87.899 us; speedup vs baseline: 1.0747x; 1.0747x over previous
//
#include <hip/hip_runtime.h>
#include <hip/hip_bf16.h>

// Problem constants (fixed by setup_inputs):
//   T=36, Q=2048, C=42 (num_classes=41), N=128
// Inputs (d_in order):
//   0: pred_logits  float32 [T*Q, C]
//   1: pred_boxes   float32 [T*Q, 4]   (cx,cy,w,h)
//   2: tgt_labels   int32   [N*T]
//   3: tgt_boxes    float32 [N*T, 4]
//   4: tgt_valid    int32   [N*T]
//   5: tgt_original_valid int32 [N*T]
// Output: float32 [Q, N] row-major, out[q*N+n]

constexpr int T = 36;
constexpr int Q = 2048;
constexpr int C = 42;
constexpr int N = 128;

// ---------------------------------------------------------------------------
// Kernel 1: row softmax of logits, written TRANSPOSED as P2[t][c][q].
// All 256 threads active in the reduction (4 threads per row), exp computed
// once (stored back into the tile). Transposed write makes kernel 2's
// class-prob gather fully coalesced (wave = 64 consecutive q, one 256B line).
// ---------------------------------------------------------------------------
__global__ __launch_bounds__(256) void softmax_transpose_kernel(
    const float* __restrict__ logits, float* __restrict__ P2) {
  constexpr int QB = 64;
  constexpr int LS = C + 1;  // 43: gcd(43,32)=1 -> conflict-free

  __shared__ float tile[QB * LS];
  __shared__ float s_max[4 * QB];
  __shared__ float s_sum[4 * QB];
  __shared__ float s_rinv[QB];

  const int t = blockIdx.y;
  const int q0 = blockIdx.x * QB;
  const int tid = threadIdx.x;

  const float* src = logits + ((size_t)t * Q + q0) * C;
  for (int i = tid; i < QB * C; i += 256) {
    int r = i / C, c = i % C;
    tile[r * LS + c] = src[i];
  }
  __syncthreads();

  // 4 threads per row: col ranges {0..10, 11..21, 22..31, 32..41}.
  const int part = tid >> 6;
  const int row = tid & 63;
  const int c0 = (part < 2) ? part * 11 : 22 + (part - 2) * 10;
  const int c1 = (part < 2) ? c0 + 11 : c0 + 10;

  float m = -1e30f;
  for (int c = c0; c < c1; ++c) m = fmaxf(m, tile[row * LS + c]);
  s_max[part * QB + row] = m;
  __syncthreads();

  m = fmaxf(fmaxf(s_max[row], s_max[QB + row]),
            fmaxf(s_max[2 * QB + row], s_max[3 * QB + row]));
  float s = 0.f;
  for (int c = c0; c < c1; ++c) {
    float e = __expf(tile[row * LS + c] - m);
    tile[row * LS + c] = e;  // single exp: reuse in the write pass
    s += e;
  }
  s_sum[part * QB + row] = s;
  __syncthreads();

  if (part == 0) {
    float stot = s_sum[row] + s_sum[QB + row] + s_sum[2 * QB + row] +
                 s_sum[3 * QB + row];
    s_rinv[row] = 1.f / stot;
  }
  __syncthreads();

  for (int i = tid; i < QB * C; i += 256) {
    int c = i >> 6;  // 0..41
    int r = i & 63;  // 0..63
    P2[(size_t)(t * C + c) * Q + q0 + r] = tile[r * LS + c] * s_rinv[r];
  }
}

// ---------------------------------------------------------------------------
// Kernel 2: cost[q,n] = sum_t valid*(l1 - prob - iou) / denom[n].
// R2-winning body (wave-uniform valid-skip branch, loads under the branch,
// tiny LDS) + t-SPLIT: block = 512 threads = 64 q-lanes x 4 n-subs x 2
// t-halves; each thread runs 18 t's, halves combined through LDS. Grid
// (32,32) = 1024 blocks x 8 waves = 32 waves/CU (max) — double R2's
// residency with half R2's per-wave serial chain.
// ---------------------------------------------------------------------------
__global__ __launch_bounds__(512) void cost_kernel(
    const float* __restrict__ P2, const float* __restrict__ pred_boxes,
    const int* __restrict__ labels, const float* __restrict__ tboxes,
    const int* __restrict__ valid, const int* __restrict__ ovalid,
    float* __restrict__ out) {
  constexpr int NB = 4;
  constexpr int RS = NB + 1;  // stride 5: gcd(5,32)=1, conflict-free

  const int q0 = blockIdx.x * 64;
  const int n0 = blockIdx.y * NB;
  const int tid = threadIdx.x;      // 0..511
  const int lane = tid & 63;        // q offset
  const int sub = (tid >> 6) & 3;   // local n (wave-uniform)
  const int half = tid >> 8;        // t-half (wave-uniform)
  const int q = q0 + lane;

  __shared__ float4 s_tb[NB * T];
  __shared__ int s_idv[NB * T];     // (valid<<8) | id
  __shared__ float s_rden[NB];      // 1/denom
  __shared__ float s_res[2 * 64 * RS];

  for (int i = tid; i < NB * T; i += 512) {
    int n = n0 + i / T;
    int t = i % T;
    int g = n * T + t;
    s_idv[i] = ((ovalid[g] == 0) ? (C - 1) : labels[g]) | (valid[g] << 8);
    s_tb[i] = ((const float4*)tboxes)[g];
  }
  if (tid < NB) {
    int n = n0 + tid;
    int s = 0;
    for (int t = 0; t < T; ++t) s += valid[n * T + t];
    s_rden[tid] = 1.f / (float)s;
  }
  __syncthreads();

  float acc = 0.f;
  const float* probs_base = P2 + q;
  const int t_begin = half * (T / 2);
  const int t_end = t_begin + (T / 2);

  for (int t = t_begin; t < t_end; ++t) {
    int pk = s_idv[sub * T + t];
    if (pk & 0x100) {  // wave-uniform: whole wave shares (n,t) -> no divergence
      float4 pb = ((const float4*)pred_boxes)[t * Q + q];
      float4 tb = s_tb[sub * T + t];
      int id = pk & 0xff;
      // Coalesced gather: 64 lanes -> 64 consecutive floats (one 256B line).
      float p = probs_base[(size_t)(t * C + id) * Q];

      float l1 = 0.25f * (fabsf(pb.x - tb.x) + fabsf(pb.y - tb.y) +
                          fabsf(pb.z - tb.z) + fabsf(pb.w - tb.w));
      float px1 = pb.x - 0.5f * pb.z, py1 = pb.y - 0.5f * pb.w;
      float px2 = pb.x + 0.5f * pb.z, py2 = pb.y + 0.5f * pb.w;
      float tx1 = tb.x - 0.5f * tb.z, ty1 = tb.y - 0.5f * tb.w;
      float tx2 = tb.x + 0.5f * tb.z, ty2 = tb.y + 0.5f * tb.w;
      float iw = fmaxf(fminf(px2, tx2) - fmaxf(px1, tx1), 0.f);
      float ih = fmaxf(fminf(py2, ty2) - fmaxf(py1, ty1), 0.f);
      float inter = iw * ih;
      float uni = pb.z * pb.w + tb.z * tb.w - inter;
      acc += l1 - p - inter / uni;
    }
  }

  // Combine t-halves, then transpose through LDS for coalesced float4 stores.
  s_res[half * (64 * RS) + lane * RS + sub] = acc;
  __syncthreads();
  if (half == 0) {
    float tot = (acc + s_res[64 * RS + lane * RS + sub]) * s_rden[sub];
    s_res[lane * RS + sub] = tot;
  }
  __syncthreads();

  if (tid < 64) {
    float4 o;
    o.x = s_res[tid * RS + 0];
    o.y = s_res[tid * RS + 1];
    o.z = s_res[tid * RS + 2];
    o.w = s_res[tid * RS + 3];
    *(float4*)(out + (size_t)(q0 + tid) * N + n0) = o;
  }
}

extern "C" void kernel_launch(void* const* d_in, const int* in_sizes, int n_in,
                              void* d_out, int out_size, void* d_ws, size_t ws_size,
                              hipStream_t stream) {
  const float* logits = (const float*)d_in[0];
  const float* pboxes = (const float*)d_in[1];
  const int* labels = (const int*)d_in[2];
  const float* tboxes = (const float*)d_in[3];
  const int* valid = (const int*)d_in[4];
  const int* ovalid = (const int*)d_in[5];
  float* out = (float*)d_out;

  // Workspace: transposed probs P2[T][C][Q] = 36*42*2048*4 B = 12.4 MB.
  float* P2 = (float*)d_ws;

  dim3 g1(Q / 64, T);
  softmax_transpose_kernel<<<g1, 256, 0, stream>>>(logits, P2);

  dim3 g2(Q / 64, N / 4);
  cost_kernel<<<g2, 512, 0, stream>>>(P2, pboxes, labels, tboxes, valid, ovalid, out);
}